// Round 4
// baseline (172.305 us; speedup 1.0000x reference)
//
#include <hip/hip_runtime.h>
#include <math.h>

// spaceGraph via f16 MFMA, round 4.
// Per (b,h,p) tile (2048): X(128x64) -> Q=X*W1^T+b1, K=X*W2^T+b2 (MFMA),
// S=Q*K^T (MFMA), A=softmax(gelu(S)) (tanh-gelu fused into exp), O=A*X (MFMA).
// L1-renorm after softmax is identity.
// R4 changes vs R3 (latency-bound: 40% unattributed stall, occupancy 17%):
//  - 512-thread blocks (8 waves, wave owns 16 rows) -> 24 waves/CU resident
//    at the same 54272B LDS (3 blocks/CU). Half the per-thread serial chain.
//  - Phase 5 computes O^T = Xt * A^T: C/D rows become consecutive dims ->
//    epilogue is 4 float4 stores per thread (was 16 scalar dwords).

namespace {
constexpr int H = 8, NV = 128, HEAD = 64, B = 4, L = 8192;
constexpr int P = L / NV;        // 64
constexpr int D = H * HEAD;      // 512
constexpr int RS = P * D;        // 32768 floats between vars j -> j+1

constexpr int XT_S = 136;        // Xt row stride (halfs); 64 rows (dims)
constexpr int QK_S = 72;         // Q/K row stride; 128 rows (vars)
constexpr int A_S  = 136;        // A row stride; 128 rows (needs <= Q+K space)

typedef _Float16 half8  __attribute__((ext_vector_type(8)));
typedef _Float16 half4v __attribute__((ext_vector_type(4)));
typedef _Float16 half2v __attribute__((ext_vector_type(2)));
typedef float    floatx4 __attribute__((ext_vector_type(4)));

__device__ __forceinline__ floatx4 mfma16(half8 a, half8 b, floatx4 c) {
    return __builtin_amdgcn_mfma_f32_16x16x32_f16(a, b, c, 0, 0, 0);
}

__device__ __forceinline__ half8 cvt8(float4 a, float4 b) {
    half8 r;
    r[0]=(_Float16)a.x; r[1]=(_Float16)a.y; r[2]=(_Float16)a.z; r[3]=(_Float16)a.w;
    r[4]=(_Float16)b.x; r[5]=(_Float16)b.y; r[6]=(_Float16)b.z; r[7]=(_Float16)b.w;
    return r;
}

// ---- pre-pass: w1,w2 fp32(64x64) -> f16 row-major in d_ws ----
__global__ __launch_bounds__(256) void pack_w(const float4* __restrict__ w1,
                                              const float4* __restrict__ w2,
                                              half4v* __restrict__ wh) {
    const int t = blockIdx.x * 256 + threadIdx.x;   // 0..1023
    const float4 a = w1[t];
    const float4 b = w2[t];
    half4v ha, hb;
    ha[0]=(_Float16)a.x; ha[1]=(_Float16)a.y; ha[2]=(_Float16)a.z; ha[3]=(_Float16)a.w;
    hb[0]=(_Float16)b.x; hb[1]=(_Float16)b.y; hb[2]=(_Float16)b.z; hb[3]=(_Float16)b.w;
    wh[t] = ha;                 // w1h: halfs [0, 4096)
    wh[1024 + t] = hb;          // w2h: halfs [4096, 8192)
}

__global__ __launch_bounds__(512, 6) void space_graph_mfma4(
    const float* __restrict__ x, const _Float16* __restrict__ wh,
    const float* __restrict__ b1, const float* __restrict__ b2,
    float* __restrict__ out)
{
    // 64*136 + 2*128*72 = 27136 halfs = 54272 B <= 163840/3 -> 3 blocks/CU
    __shared__ _Float16 lds[64 * XT_S + 2 * NV * QK_S];
    _Float16* Xt = lds;                  // X^T: [dim][var]
    _Float16* Qh = lds + 64 * XT_S;      // Q:   [var][dim]
    _Float16* Kh = Qh + NV * QK_S;       // K:   [var][dim]
    _Float16* A  = Qh;                   // A(128 x A_S) aliases Q+K after phase 3

    const int t    = threadIdx.x;
    const int lane = t & 63;
    const int w    = t >> 6;             // wave 0..7 -> owns S/O rows 16w..16w+15
    const int col  = lane & 15;
    const int quad = lane >> 4;

    const int blk = blockIdx.x;
    const int p = blk & (P - 1);
    const int h = (blk >> 6) & (H - 1);
    const int b = blk >> 9;
    const size_t base = ((size_t)b * L + (size_t)p) * D + (size_t)h * HEAD;

    // ---- Phase 1: build Xt (f16 transposed X); 512 thr -> 32 row-pairs/iter ----
    {
        const int c  = t & 15;           // float4 column
        const int tt = t >> 4;           // 0..31
        #pragma unroll
        for (int it = 0; it < 2; ++it) {
            const int j0 = 2 * tt + 64 * it;
            const float4 v0 = *(const float4*)(x + base + (size_t)j0 * RS + c * 4);
            const float4 v1 = *(const float4*)(x + base + (size_t)(j0 + 1) * RS + c * 4);
            const float va[4] = {v0.x, v0.y, v0.z, v0.w};
            const float vb[4] = {v1.x, v1.y, v1.z, v1.w};
            #pragma unroll
            for (int q = 0; q < 4; ++q) {
                half2v pr; pr[0] = (_Float16)va[q]; pr[1] = (_Float16)vb[q];
                *(half2v*)&Xt[(4 * c + q) * XT_S + j0] = pr;
            }
        }
    }
    // no barrier: Xt first read in phase 5; phase-2-end barrier covers it.

    // ---- Phase 2: Q = X*W1^T + b1, K = X*W2^T + b2 (wave w: rows 16w..) ----
    floatx4 qacc[4], kacc[4];
    #pragma unroll
    for (int nt = 0; nt < 4; ++nt) { qacc[nt] = (floatx4)0.0f; kacc[nt] = (floatx4)0.0f; }

    half8 axf[2];  // X A-frags straight from global (L1/L2-hot from phase 1)
    #pragma unroll
    for (int ks = 0; ks < 2; ++ks) {
        const int row = 16 * w + col;
        const float* src = x + base + (size_t)row * RS + quad * 8 + 32 * ks;
        axf[ks] = cvt8(*(const float4*)src, *(const float4*)(src + 4));
    }

    const _Float16* w1h = wh;
    const _Float16* w2h = wh + HEAD * HEAD;
    #pragma unroll
    for (int ks = 0; ks < 2; ++ks)
        #pragma unroll
        for (int nt = 0; nt < 4; ++nt) {
            const int n = col + 16 * nt, k0 = quad * 8 + 32 * ks;
            const half8 wb1 = *(const half8*)&w1h[n * HEAD + k0];
            const half8 wb2 = *(const half8*)&w2h[n * HEAD + k0];
            qacc[nt] = mfma16(axf[ks], wb1, qacc[nt]);
            kacc[nt] = mfma16(axf[ks], wb2, kacc[nt]);
        }

    #pragma unroll
    for (int r = 0; r < 4; ++r) {
        const int R = 16 * w + quad * 4 + r;
        _Float16* qrow = &Qh[R * QK_S + col];
        _Float16* krow = &Kh[R * QK_S + col];
        #pragma unroll
        for (int nt = 0; nt < 4; ++nt) {
            qrow[nt * 16] = (_Float16)(qacc[nt][r] + b1[col + 16 * nt]);
            krow[nt * 16] = (_Float16)(kacc[nt][r] + b2[col + 16 * nt]);
        }
    }
    __syncthreads();

    // ---- Phase 3: S = Q*K^T (wave w: rows 16w..16w+15, all 128 cols) ----
    floatx4 sacc[8];
    #pragma unroll
    for (int nt = 0; nt < 8; ++nt) sacc[nt] = (floatx4)0.0f;

    #pragma unroll
    for (int ks = 0; ks < 2; ++ks) {
        const half8 qaf = *(const half8*)&Qh[(16 * w + col) * QK_S + quad * 8 + 32 * ks];
        #pragma unroll
        for (int nt = 0; nt < 8; ++nt) {
            const half8 kbf = *(const half8*)&Kh[(col + 16 * nt) * QK_S + quad * 8 + 32 * ks];
            sacc[nt] = mfma16(qaf, kbf, sacc[nt]);
        }
    }
    __syncthreads();  // all waves done reading Qh/Kh before A overwrites them

    // ---- Phase 4: A = softmax(gelu(S)); fast tanh-gelu fused into exp ----
    //   u = s*(0.79788456 + 0.035677408*s^2); g = s/(1+e^{-2u}); e = e^g.
    // Large |s| safe: e^{+inf}->den=inf->rcp=0->g=0->e=1 (gelu(-big)=0).
    #pragma unroll
    for (int r = 0; r < 4; ++r) {
        float wv[8]; float rs = 0.f;
        #pragma unroll
        for (int nt = 0; nt < 8; ++nt) {
            const float s  = sacc[nt][r];
            const float u  = s * fmaf(s * s, 0.035677408137f, 0.7978845608f);
            const float em = __expf(-2.0f * u);
            const float g  = s * __builtin_amdgcn_rcpf(1.0f + em);
            const float e  = __expf(g);
            wv[nt] = e; rs += e;
        }
        rs += __shfl_xor(rs, 1); rs += __shfl_xor(rs, 2);
        rs += __shfl_xor(rs, 4); rs += __shfl_xor(rs, 8);
        const float inv = __builtin_amdgcn_rcpf(rs);
        const int R = 16 * w + quad * 4 + r;
        _Float16* arow = &A[R * A_S + col];
        #pragma unroll
        for (int nt = 0; nt < 8; ++nt)
            arow[nt * 16] = (_Float16)(wv[nt] * inv);
    }
    // no barrier: wave w reads back only its own 16 A rows (wave-private).

    // ---- Phase 5: O^T = Xt * A^T. A-op: Xt[m=dim][k=var]; B-op: A row-major
    // (n = var i = 16w+col, wave-private rows). C/D: row = dim (consecutive!),
    // col = i -> float4 stores.
    floatx4 oacc[4];
    #pragma unroll
    for (int mt = 0; mt < 4; ++mt) oacc[mt] = (floatx4)0.0f;

    #pragma unroll
    for (int ks = 0; ks < 4; ++ks) {
        const half8 bf = *(const half8*)&A[(16 * w + col) * A_S + quad * 8 + 32 * ks];
        #pragma unroll
        for (int mt = 0; mt < 4; ++mt) {
            const half8 af = *(const half8*)&Xt[(16 * mt + col) * XT_S + quad * 8 + 32 * ks];
            oacc[mt] = mfma16(af, bf, oacc[mt]);
        }
    }

    // ---- Epilogue: 4 float4 stores; lane stores dims 16mt+quad*4..+3 of var i ----
    {
        const size_t rowoff = base + (size_t)(16 * w + col) * RS + quad * 4;
        #pragma unroll
        for (int mt = 0; mt < 4; ++mt) {
            float4 v; v.x = oacc[mt][0]; v.y = oacc[mt][1];
            v.z = oacc[mt][2]; v.w = oacc[mt][3];
            *(float4*)(out + rowoff + 16 * mt) = v;
        }
    }
}
} // namespace

extern "C" void kernel_launch(void* const* d_in, const int* in_sizes, int n_in,
                              void* d_out, int out_size, void* d_ws, size_t ws_size,
                              hipStream_t stream) {
    const float* x  = (const float*)d_in[0];
    const float* w1 = (const float*)d_in[1];
    const float* b1 = (const float*)d_in[2];
    const float* w2 = (const float*)d_in[3];
    const float* b2 = (const float*)d_in[4];
    float* out = (float*)d_out;
    _Float16* wh = (_Float16*)d_ws;   // 16KB: w1h | w2h (f16 row-major)

    hipLaunchKernelGGL(pack_w, dim3(4), dim3(256), 0, stream,
                       (const float4*)w1, (const float4*)w2, (half4v*)wh);
    hipLaunchKernelGGL(space_graph_mfma4, dim3(B * H * P), dim3(512), 0, stream,
                       x, wh, b1, b2, out);
}

// Round 5
// 150.453 us; speedup vs baseline: 1.1452x; 1.1452x over previous
//
#include <hip/hip_runtime.h>
#include <math.h>

// spaceGraph via f16 MFMA, round 5.
// Per (b,h,p) tile (2048): X(128x64) -> Q=X*W1^T+b1, K=X*W2^T+b2 (MFMA),
// S=Q*K^T (MFMA), A=softmax(gelu(S)), O=A*X (MFMA). L1-renorm = identity.
// R5 = R3 skeleton (4 waves, 32 rows/wave: max operand reuse — R4's 16-row
// waves doubled LDS reads/MFMA and regressed) + fixes:
//  - Phase 5 computes O^T = Xt*A^T -> epilogue 8 float4 stores (was 32 dwords).
//  - Softmax: constants pre-folded with -2*log2e, raw v_exp_f32 via
//    __builtin_amdgcn_exp2f: 3 trans + ~6 VALU per elem.
//  - Normalize in registers BEFORE the WAR barrier; A-writes after -> exp VALU
//    overlaps other waves' MFMA; A rows stay wave-private (no 3rd barrier).

namespace {
constexpr int H = 8, NV = 128, HEAD = 64, B = 4, L = 8192;
constexpr int P = L / NV;        // 64
constexpr int D = H * HEAD;      // 512
constexpr int RS = P * D;        // 32768 floats between vars j -> j+1

constexpr int XT_S = 136;        // Xt row stride (halfs); 64 rows (dims)
constexpr int QK_S = 72;         // Q/K row stride; 128 rows (vars)
constexpr int A_S  = 136;        // A row stride; 128 rows (aliases Q+K)

typedef _Float16 half8  __attribute__((ext_vector_type(8)));
typedef _Float16 half4v __attribute__((ext_vector_type(4)));
typedef _Float16 half2v __attribute__((ext_vector_type(2)));
typedef float    floatx4 __attribute__((ext_vector_type(4)));

__device__ __forceinline__ floatx4 mfma16(half8 a, half8 b, floatx4 c) {
    return __builtin_amdgcn_mfma_f32_16x16x32_f16(a, b, c, 0, 0, 0);
}

__device__ __forceinline__ half8 cvt8(float4 a, float4 b) {
    half8 r;
    r[0]=(_Float16)a.x; r[1]=(_Float16)a.y; r[2]=(_Float16)a.z; r[3]=(_Float16)a.w;
    r[4]=(_Float16)b.x; r[5]=(_Float16)b.y; r[6]=(_Float16)b.z; r[7]=(_Float16)b.w;
    return r;
}

// ---- pre-pass: w1,w2 fp32(64x64) -> f16 row-major in d_ws ----
__global__ __launch_bounds__(256) void pack_w(const float4* __restrict__ w1,
                                              const float4* __restrict__ w2,
                                              half4v* __restrict__ wh) {
    const int t = blockIdx.x * 256 + threadIdx.x;   // 0..1023
    const float4 a = w1[t];
    const float4 b = w2[t];
    half4v ha, hb;
    ha[0]=(_Float16)a.x; ha[1]=(_Float16)a.y; ha[2]=(_Float16)a.z; ha[3]=(_Float16)a.w;
    hb[0]=(_Float16)b.x; hb[1]=(_Float16)b.y; hb[2]=(_Float16)b.z; hb[3]=(_Float16)b.w;
    wh[t] = ha;                 // w1h: halfs [0, 4096)
    wh[1024 + t] = hb;          // w2h: halfs [4096, 8192)
}

__global__ __launch_bounds__(256, 3) void space_graph_mfma5(
    const float* __restrict__ x, const _Float16* __restrict__ wh,
    const float* __restrict__ b1, const float* __restrict__ b2,
    float* __restrict__ out)
{
    // 64*136 + 2*128*72 = 27136 halfs = 54272 B -> 3 blocks/CU (162816<=163840)
    __shared__ _Float16 lds[64 * XT_S + 2 * NV * QK_S];
    _Float16* Xt = lds;                  // X^T: [dim][var]
    _Float16* Qh = lds + 64 * XT_S;      // Q:   [var][dim]
    _Float16* Kh = Qh + NV * QK_S;       // K:   [var][dim]
    _Float16* A  = Qh;                   // A(128 x A_S) aliases Q+K after barrier2

    const int t    = threadIdx.x;
    const int lane = t & 63;
    const int w    = t >> 6;             // wave 0..3 -> owns S/O rows 32w..32w+31
    const int col  = lane & 15;
    const int quad = lane >> 4;

    const int blk = blockIdx.x;
    const int p = blk & (P - 1);
    const int h = (blk >> 6) & (H - 1);
    const int b = blk >> 9;
    const size_t base = ((size_t)b * L + (size_t)p) * D + (size_t)h * HEAD;

    // ---- Phase 1: build Xt (f16 transposed X) ----
    {
        const int c  = t & 15;           // float4 column
        const int tt = t >> 4;
        #pragma unroll
        for (int it = 0; it < 4; ++it) {
            const int j0 = 2 * (tt + 16 * it);
            const float4 v0 = *(const float4*)(x + base + (size_t)j0 * RS + c * 4);
            const float4 v1 = *(const float4*)(x + base + (size_t)(j0 + 1) * RS + c * 4);
            const float va[4] = {v0.x, v0.y, v0.z, v0.w};
            const float vb[4] = {v1.x, v1.y, v1.z, v1.w};
            #pragma unroll
            for (int q = 0; q < 4; ++q) {
                half2v pr; pr[0] = (_Float16)va[q]; pr[1] = (_Float16)vb[q];
                *(half2v*)&Xt[(4 * c + q) * XT_S + j0] = pr;
            }
        }
    }
    // no barrier: Xt first read in phase 5; phase-2-end barrier covers it.

    // ---- Phase 2: Q = X*W1^T + b1, K = X*W2^T + b2 ----
    floatx4 qacc[2][4], kacc[2][4];
    #pragma unroll
    for (int mt = 0; mt < 2; ++mt)
        #pragma unroll
        for (int nt = 0; nt < 4; ++nt) { qacc[mt][nt] = (floatx4)0.0f; kacc[mt][nt] = (floatx4)0.0f; }

    half8 axf[2][2];  // X A-frags straight from global (L2-hot from phase 1)
    #pragma unroll
    for (int mt = 0; mt < 2; ++mt)
        #pragma unroll
        for (int ks = 0; ks < 2; ++ks) {
            const int row = 32 * w + 16 * mt + col;
            const float* src = x + base + (size_t)row * RS + quad * 8 + 32 * ks;
            axf[mt][ks] = cvt8(*(const float4*)src, *(const float4*)(src + 4));
        }

    const _Float16* w1h = wh;
    const _Float16* w2h = wh + HEAD * HEAD;
    #pragma unroll
    for (int ks = 0; ks < 2; ++ks)
        #pragma unroll
        for (int nt = 0; nt < 4; ++nt) {
            const int n = col + 16 * nt, k0 = quad * 8 + 32 * ks;
            const half8 wb1 = *(const half8*)&w1h[n * HEAD + k0];
            const half8 wb2 = *(const half8*)&w2h[n * HEAD + k0];
            #pragma unroll
            for (int mt = 0; mt < 2; ++mt) {
                qacc[mt][nt] = mfma16(axf[mt][ks], wb1, qacc[mt][nt]);
                kacc[mt][nt] = mfma16(axf[mt][ks], wb2, kacc[mt][nt]);
            }
        }

    float bb1[4], bb2[4];
    #pragma unroll
    for (int nt = 0; nt < 4; ++nt) { bb1[nt] = b1[col + 16 * nt]; bb2[nt] = b2[col + 16 * nt]; }
    #pragma unroll
    for (int mt = 0; mt < 2; ++mt)
        #pragma unroll
        for (int r = 0; r < 4; ++r) {
            const int R = 32 * w + 16 * mt + quad * 4 + r;
            _Float16* qrow = &Qh[R * QK_S + col];
            _Float16* krow = &Kh[R * QK_S + col];
            #pragma unroll
            for (int nt = 0; nt < 4; ++nt) {
                qrow[nt * 16] = (_Float16)(qacc[mt][nt][r] + bb1[nt]);
                krow[nt * 16] = (_Float16)(kacc[mt][nt][r] + bb2[nt]);
            }
        }
    __syncthreads();

    // ---- Phase 3: S = Q*K^T (wave w: rows 32w..32w+31) ----
    floatx4 sacc[2][8];
    #pragma unroll
    for (int mt = 0; mt < 2; ++mt)
        #pragma unroll
        for (int nt = 0; nt < 8; ++nt) sacc[mt][nt] = (floatx4)0.0f;

    #pragma unroll
    for (int ks = 0; ks < 2; ++ks) {
        half8 qaf[2];
        #pragma unroll
        for (int mt = 0; mt < 2; ++mt)
            qaf[mt] = *(const half8*)&Qh[(32 * w + 16 * mt + col) * QK_S + quad * 8 + 32 * ks];
        #pragma unroll
        for (int nt = 0; nt < 8; ++nt) {
            const half8 kbf = *(const half8*)&Kh[(col + 16 * nt) * QK_S + quad * 8 + 32 * ks];
            #pragma unroll
            for (int mt = 0; mt < 2; ++mt)
                sacc[mt][nt] = mfma16(qaf[mt], kbf, sacc[mt][nt]);
        }
    }

    // ---- Phase 4a (registers, pre-barrier): A = softmax(gelu(S)) into sacc ----
    // exp(gelu(s)) with -2*log2e folded into the tanh-gelu polynomial:
    //   a   = s*(C1 + C3*s^2)            ( = -2u*log2e )
    //   em  = 2^a = e^{-2u}
    //   g2  = (s*log2e) / (1+em)         ( = gelu(s)*log2e )
    //   e   = 2^g2 = e^{gelu(s)}
    // Tails: s->-inf: a->+inf, em=inf, rcp=0, e=2^0=1 (=e^{gelu}=e^0). s->+inf:
    // a->-inf, em=0, e=e^s. Both exact.
    #pragma unroll
    for (int mt = 0; mt < 2; ++mt)
        #pragma unroll
        for (int r = 0; r < 4; ++r) {
            float rs = 0.f;
            #pragma unroll
            for (int nt = 0; nt < 8; ++nt) {
                const float s  = sacc[mt][nt][r];
                const float a  = s * fmaf(s * s, -0.1029534f, -2.3022083f);
                const float em = __builtin_amdgcn_exp2f(a);
                const float g2 = (s * 1.44269504089f) * __builtin_amdgcn_rcpf(1.0f + em);
                const float e  = __builtin_amdgcn_exp2f(g2);
                sacc[mt][nt][r] = e; rs += e;
            }
            rs += __shfl_xor(rs, 1); rs += __shfl_xor(rs, 2);
            rs += __shfl_xor(rs, 4); rs += __shfl_xor(rs, 8);
            const float inv = __builtin_amdgcn_rcpf(rs);
            #pragma unroll
            for (int nt = 0; nt < 8; ++nt) sacc[mt][nt][r] *= inv;
        }

    __syncthreads();  // WAR: all waves done reading Qh/Kh; now A may overwrite

    // ---- Phase 4b: write A (f16) to LDS; rows are wave-private ----
    #pragma unroll
    for (int mt = 0; mt < 2; ++mt)
        #pragma unroll
        for (int r = 0; r < 4; ++r) {
            const int R = 32 * w + 16 * mt + quad * 4 + r;
            _Float16* arow = &A[R * A_S + col];
            #pragma unroll
            for (int nt = 0; nt < 8; ++nt)
                arow[nt * 16] = (_Float16)sacc[mt][nt][r];
        }
    // no barrier: wave w reads back only its own 32 A rows below.

    // ---- Phase 5: O^T = Xt * A^T. A-op: Xt[m=dim][k=var]; B-op: A row-major
    // (n = var i in wave's 32 rows). C/D: row = dim (consecutive per quad),
    // col = var -> float4 stores.
    floatx4 oacc[4][2];  // [mt=dim-tile 0..3][nt=var-tile 0..1]
    #pragma unroll
    for (int mt = 0; mt < 4; ++mt)
        #pragma unroll
        for (int nt = 0; nt < 2; ++nt) oacc[mt][nt] = (floatx4)0.0f;

    #pragma unroll
    for (int ks = 0; ks < 4; ++ks) {
        half8 bf[2];
        #pragma unroll
        for (int nt = 0; nt < 2; ++nt)
            bf[nt] = *(const half8*)&A[(32 * w + 16 * nt + col) * A_S + quad * 8 + 32 * ks];
        #pragma unroll
        for (int mt = 0; mt < 4; ++mt) {
            const half8 af = *(const half8*)&Xt[(16 * mt + col) * XT_S + quad * 8 + 32 * ks];
            #pragma unroll
            for (int nt = 0; nt < 2; ++nt)
                oacc[mt][nt] = mfma16(af, bf[nt], oacc[mt][nt]);
        }
    }

    // ---- Epilogue: 8 float4 stores; quads cover 64B segments of each var ----
    #pragma unroll
    for (int nt = 0; nt < 2; ++nt) {
        const size_t rowoff = base + (size_t)(32 * w + 16 * nt + col) * RS + quad * 4;
        #pragma unroll
        for (int mt = 0; mt < 4; ++mt) {
            float4 v; v.x = oacc[mt][nt][0]; v.y = oacc[mt][nt][1];
            v.z = oacc[mt][nt][2]; v.w = oacc[mt][nt][3];
            *(float4*)(out + rowoff + 16 * mt) = v;
        }
    }
}
} // namespace

extern "C" void kernel_launch(void* const* d_in, const int* in_sizes, int n_in,
                              void* d_out, int out_size, void* d_ws, size_t ws_size,
                              hipStream_t stream) {
    const float* x  = (const float*)d_in[0];
    const float* w1 = (const float*)d_in[1];
    const float* b1 = (const float*)d_in[2];
    const float* w2 = (const float*)d_in[3];
    const float* b2 = (const float*)d_in[4];
    float* out = (float*)d_out;
    _Float16* wh = (_Float16*)d_ws;   // 16KB: w1h | w2h (f16 row-major)

    hipLaunchKernelGGL(pack_w, dim3(4), dim3(256), 0, stream,
                       (const float4*)w1, (const float4*)w2, (half4v*)wh);
    hipLaunchKernelGGL(space_graph_mfma5, dim3(B * H * P), dim3(256), 0, stream,
                       x, wh, b1, b2, out);
}